// Round 15
// baseline (160.079 us; speedup 1.0000x reference)
//
#include <hip/hip_runtime.h>
#include <hip/hip_bf16.h>
#include <math.h>

#define BATCH   16
#define SEQL    512
#define NVARS   32
#define PATCHL  16
#define LTOK    32
#define DMODEL  128
#define NLAYER  2
#define DIN     256
#define DSTATE  16
#define DTRANK  8
#define DCONV   4
#define PRED    96
#define TOK     1024
#define NTOK    (BATCH*TOK)   // 16384
#define EPSF    1e-5f
#define NCH     64            // time chunks
#define CHL     16            // TOK/NCH

#define NIW (NLAYER * 2 * DIN * DMODEL)          // 131072
#define NXW (NLAYER * (DTRANK + 2*DSTATE) * DIN) // 20480
#define NOW (NLAYER * DMODEL * DIN)              // 65536
#define NHW (PRED * LTOK * DMODEL)               // 393216
#define TOTW (NIW + NXW + NOW + NHW)

typedef __attribute__((ext_vector_type(8))) short bf16x8;
typedef __attribute__((ext_vector_type(4))) float f32x4;
typedef __hip_bfloat16 bf16;

__device__ __forceinline__ float softplus_f(float x) {
    return (x > 8.f) ? x : __logf(1.f + __expf(x));
}

// ---------------------------------------------------------------------------
// K0: merged init (instnorm+patch+rmsnorm0 | weight cast + consts + hg zero)
// ---------------------------------------------------------------------------
__global__ __launch_bounds__(256) void k_init(
    const float* __restrict__ x_enc, const float* __restrict__ patch_w,
    const float* __restrict__ nw0,
    const float* __restrict__ in_w, const float* __restrict__ xp_w,
    const float* __restrict__ out_w, const float* __restrict__ head_w,
    const float* __restrict__ A_log,
    float* __restrict__ x, bf16* __restrict__ hbf,
    float* __restrict__ means, float* __restrict__ stdev,
    bf16* __restrict__ wbf, float* __restrict__ a1s, int* __restrict__ pwf,
    float* __restrict__ hg)
{
    __shared__ float xe[SEQL];
    __shared__ float pw[DMODEL * PATCHL];
    __shared__ float red[8];
    __shared__ float enc_lds[LTOK][DMODEL];
    int tid = threadIdx.x;

    if (blockIdx.x >= BATCH * NVARS) {
        int i = (blockIdx.x - BATCH * NVARS) * 256 + tid;
        if (i < TOTW) {
            float v;
            if (i < NIW) v = in_w[i];
            else if (i < NIW + NXW) v = xp_w[i - NIW];
            else if (i < NIW + NXW + NOW) v = out_w[i - NIW - NXW];
            else v = head_w[i - NIW - NXW - NOW];
            wbf[i] = __float2bfloat16(v);
        } else if (i < TOTW + NLAYER * DIN) {
            int j = i - TOTW;
            const float* al = A_log + (size_t)j * DSTATE;
            float a1 = -__expf(al[0]);
            bool pwok = true;
            #pragma unroll
            for (int n = 1; n < 16; n++) {
                float av = -__expf(al[n]);
                pwok = pwok && (fabsf(av - (n + 1) * a1) <= 1e-5f * fabsf((n + 1) * a1));
            }
            a1s[j] = a1;
            pwf[j] = pwok ? 1 : 0;
        } else if (i < TOTW + NLAYER * DIN + 512 * PRED) {
            hg[i - TOTW - NLAYER * DIN] = 0.f;
        }
        return;
    }

    int bc = blockIdx.x;
    int b = bc >> 5, c = bc & 31;

    float v0 = x_enc[((size_t)b * SEQL + tid) * NVARS + c];
    float v1 = x_enc[((size_t)b * SEQL + tid + 256) * NVARS + c];
    for (int i = tid; i < DMODEL * PATCHL; i += 256) pw[i] = patch_w[i];

    float s = v0 + v1;
    for (int o = 1; o < 64; o <<= 1) s += __shfl_xor(s, o, 64);
    if ((tid & 63) == 0) red[tid >> 6] = s;
    __syncthreads();
    float mean = (red[0] + red[1] + red[2] + red[3]) * (1.f / 512.f);

    float d0 = v0 - mean, d1 = v1 - mean;
    float q = d0 * d0 + d1 * d1;
    for (int o = 1; o < 64; o <<= 1) q += __shfl_xor(q, o, 64);
    if ((tid & 63) == 0) red[4 + (tid >> 6)] = q;
    __syncthreads();
    float var = (red[4] + red[5] + red[6] + red[7]) * (1.f / 512.f);
    float sd = sqrtf(var + EPSF);
    float rsd = 1.f / sd;
    if (tid == 0) { means[bc] = mean; stdev[bc] = sd; }

    xe[tid] = d0 * rsd;
    xe[tid + 256] = d1 * rsd;
    __syncthreads();

    size_t base = ((size_t)b * TOK + (size_t)c * LTOK) * DMODEL;
    for (int o = tid; o < LTOK * DMODEL; o += 256) {
        int l = o >> 7, dm = o & 127;
        float acc = 0.f;
        #pragma unroll
        for (int p = 0; p < PATCHL; p++) acc += xe[l * PATCHL + p] * pw[dm * PATCHL + p];
        x[base + o] = acc;
        enc_lds[l][dm] = acc;
    }
    __syncthreads();

    int t = tid >> 3, g = tid & 7;
    float vals[16];
    float ss = 0.f;
    #pragma unroll
    for (int j = 0; j < 16; j++) { vals[j] = enc_lds[t][g * 16 + j]; ss += vals[j] * vals[j]; }
    ss += __shfl_xor(ss, 1, 64);
    ss += __shfl_xor(ss, 2, 64);
    ss += __shfl_xor(ss, 4, 64);
    float rms = rsqrtf(ss * (1.f / DMODEL) + EPSF);
    bf16* hp = hbf + (base + (size_t)t * DMODEL);
    #pragma unroll
    for (int j = 0; j < 16; j++)
        hp[g * 16 + j] = __float2bfloat16(vals[j] * rms * nw0[g * 16 + j]);
}

// ---------------------------------------------------------------------------
// head GEMM (split-K atomicAdd)
// ---------------------------------------------------------------------------
__global__ __launch_bounds__(256) void mfma_gemm_at(
    const bf16* __restrict__ A, const bf16* __restrict__ W,
    float* __restrict__ C, int M, int N, int K, int kper)
{
    __shared__ ushort Asm[128][40];
    __shared__ ushort Wsm[128][40];
    int bm = blockIdx.y * 128, bn = blockIdx.x * 128;
    int tid = threadIdx.x;
    int w = tid >> 6, l = tid & 63;
    int wr = w >> 1, wc = w & 1;
    int kb = (l >> 4) * 8, lr = l & 15;

    f32x4 acc[4][4];
    #pragma unroll
    for (int i = 0; i < 4; i++)
        #pragma unroll
        for (int j = 0; j < 4; j++) acc[i][j] = (f32x4){0.f, 0.f, 0.f, 0.f};

    int kbeg = blockIdx.z * kper;
    for (int k0 = kbeg; k0 < kbeg + kper; k0 += 32) {
        #pragma unroll
        for (int i = 0; i < 2; i++) {
            int idx = tid + 256 * i;
            int row = idx >> 2, kq = (idx & 3) * 8;
            *(float4*)&Asm[row][kq] =
                *(const float4*)&A[(size_t)(bm + row) * K + k0 + kq];
            float4 wv = make_float4(0.f, 0.f, 0.f, 0.f);
            if (bn + row < N)
                wv = *(const float4*)&W[(size_t)(bn + row) * K + k0 + kq];
            *(float4*)&Wsm[row][kq] = wv;
        }
        __syncthreads();
        bf16x8 af[4], bfr[4];
        #pragma unroll
        for (int f = 0; f < 4; f++) {
            af[f]  = *(const bf16x8*)&Asm[wr * 64 + f * 16 + lr][kb];
            bfr[f] = *(const bf16x8*)&Wsm[wc * 64 + f * 16 + lr][kb];
        }
        #pragma unroll
        for (int mf = 0; mf < 4; mf++)
            #pragma unroll
            for (int nf = 0; nf < 4; nf++)
                acc[mf][nf] = __builtin_amdgcn_mfma_f32_16x16x32_bf16(
                    af[mf], bfr[nf], acc[mf][nf], 0, 0, 0);
        __syncthreads();
    }

    int rbase = bm + wr * 64 + (l >> 4) * 4;
    int cbase = bn + wc * 64 + lr;
    #pragma unroll
    for (int mf = 0; mf < 4; mf++) {
        #pragma unroll
        for (int nf = 0; nf < 4; nf++) {
            int n = cbase + nf * 16;
            if (n >= N) continue;
            #pragma unroll
            for (int r = 0; r < 4; r++)
                atomicAdd(&C[(size_t)(rbase + mf * 16 + r) * N + n], acc[mf][nf][r]);
        }
    }
}

// ---------------------------------------------------------------------------
// K4: fused in_proj(xs+z) MFMA + conv+SiLU + x_proj MFMA + scan1.
// z (own rows) computed here with the already-staged hb; packed into udb2.
// LDS regions: hb[0,8704) xs[8704,25600) | u over hb [0,8448),
// z over xs-head [8704,17152), xdbl [17152,19712).
// ---------------------------------------------------------------------------
__global__ __launch_bounds__(256) void k_convx1(
    const bf16* __restrict__ hbf, const bf16* __restrict__ iwA,
    const bf16* __restrict__ iwZ,
    const float* __restrict__ cw, const float* __restrict__ cb,
    const bf16* __restrict__ xw,
    const float* __restrict__ dtw, const float* __restrict__ dtb_,
    const float* __restrict__ a1s, const int* __restrict__ pwf,
    const float* __restrict__ A_log,
    uint2* __restrict__ udb, float* __restrict__ xdbl,
    bf16* __restrict__ q, float* __restrict__ sdt_out)
{
    int blk = blockIdx.x;              // b*NCH + ch
    int b = blk >> 6, ch = blk & (NCH - 1);
    int d = threadIdx.x;
    __shared__ __align__(16) char smem[25600];
    ushort (*hb_lds)[136] = (ushort(*)[136])smem;            // A (8704 B)
    ushort (*xs_lds)[264] = (ushort(*)[264])(smem + 8704);   // A-B (16896 B)
    ushort (*u_lds)[264]  = (ushort(*)[264])smem;            // C+ over hb
    ushort (*z_lds)[264]  = (ushort(*)[264])(smem + 8704);   // D+ over xs head
    float  (*xdbl_lds)[40] = (float(*)[40])(smem + 17152);   // D+ over xs tail

    int tloc0 = ch * CHL;

    // ---- [A] stage hbf tile (zero for tl<0) ----
    {
        int r = d >> 3, c8 = (d & 7) * 16;
        int tl = tloc0 - 16 + r;
        float4 v0 = make_float4(0.f, 0.f, 0.f, 0.f), v1 = v0;
        if (tl >= 0) {
            const bf16* src = hbf + ((size_t)b * TOK + tl) * DMODEL + c8;
            v0 = *(const float4*)src;
            v1 = *(const float4*)(src + 8);
        }
        *(float4*)&hb_lds[r][c8] = v0;
        *(float4*)&hb_lds[r][c8 + 8] = v1;
    }
    __syncthreads();

    // ---- [B] xs = hbf @ iwA^T (M=32) and z = hbf(own) @ iwZ^T (M=16) ----
    int w = d >> 6, l = d & 63;
    int lr = l & 15, kb = (l >> 4) * 8;
    f32x4 accz[4];
    #pragma unroll
    for (int nf = 0; nf < 4; nf++) accz[nf] = (f32x4){0.f, 0.f, 0.f, 0.f};
    {
        f32x4 accx[2][4];
        #pragma unroll
        for (int mf = 0; mf < 2; mf++)
            #pragma unroll
            for (int nf = 0; nf < 4; nf++) accx[mf][nf] = (f32x4){0.f, 0.f, 0.f, 0.f};
        #pragma unroll
        for (int ks = 0; ks < 4; ks++) {
            bf16x8 af0 = *(const bf16x8*)&hb_lds[lr][ks * 32 + kb];
            bf16x8 af1 = *(const bf16x8*)&hb_lds[16 + lr][ks * 32 + kb];
            #pragma unroll
            for (int nf = 0; nf < 4; nf++) {
                const bf16* wrowA = iwA + (size_t)(w * 64 + nf * 16 + lr) * DMODEL;
                const bf16* wrowZ = iwZ + (size_t)(w * 64 + nf * 16 + lr) * DMODEL;
                bf16x8 bA = *(const bf16x8*)&wrowA[ks * 32 + kb];
                bf16x8 bZ = *(const bf16x8*)&wrowZ[ks * 32 + kb];
                accx[0][nf] = __builtin_amdgcn_mfma_f32_16x16x32_bf16(af0, bA, accx[0][nf], 0, 0, 0);
                accx[1][nf] = __builtin_amdgcn_mfma_f32_16x16x32_bf16(af1, bA, accx[1][nf], 0, 0, 0);
                accz[nf]    = __builtin_amdgcn_mfma_f32_16x16x32_bf16(af1, bZ, accz[nf],    0, 0, 0);
            }
        }
        __syncthreads();   // hb reads complete before u overwrites
        #pragma unroll
        for (int mf = 0; mf < 2; mf++)
            #pragma unroll
            for (int nf = 0; nf < 4; nf++) {
                int ncol = w * 64 + nf * 16 + lr;
                #pragma unroll
                for (int r = 0; r < 4; r++) {
                    int row = mf * 16 + (l >> 4) * 4 + r;
                    bf16 xb = __float2bfloat16(accx[mf][nf][r]);
                    xs_lds[row][ncol] = *(ushort*)&xb;
                }
            }
    }
    __syncthreads();

    // ---- [C] conv + SiLU -> u_lds (over dead hb); xs still live ----
    {
        float c0 = cw[d * 4], c1 = cw[d * 4 + 1], c2 = cw[d * 4 + 2], c3 = cw[d * 4 + 3];
        float cbias = cb[d];
        float xv[19];
        #pragma unroll
        for (int i = 0; i < 19; i++) {
            ushort raw = xs_lds[13 + i][d];
            xv[i] = __bfloat162float(*(bf16*)&raw);
        }
        #pragma unroll
        for (int t = 0; t < 16; t++) {
            float a = cbias + xv[t] * c0 + xv[t + 1] * c1 + xv[t + 2] * c2 + xv[t + 3] * c3;
            float s = __fdividef(a, 1.f + __expf(-a));
            bf16 ub = __float2bfloat16(s);
            u_lds[t][d] = *(ushort*)&ub;
        }
    }
    __syncthreads();

    // ---- [D] xs dead: write z_lds; x_proj MFMA -> xdbl_lds ----
    {
        #pragma unroll
        for (int nf = 0; nf < 4; nf++) {
            int ncol = w * 64 + nf * 16 + lr;
            #pragma unroll
            for (int r = 0; r < 4; r++) {
                bf16 zb = __float2bfloat16(accz[nf][r]);
                z_lds[(l >> 4) * 4 + r][ncol] = *(ushort*)&zb;
            }
        }
        if (w < 3) {
            int nrow = w * 16 + lr;
            bool valid = nrow < 40;
            const bf16* wrow = xw + (size_t)nrow * 256;
            f32x4 acc = (f32x4){0.f, 0.f, 0.f, 0.f};
            #pragma unroll
            for (int ks = 0; ks < 8; ks++) {
                bf16x8 af = *(const bf16x8*)&u_lds[lr][ks * 32 + kb];
                bf16x8 bfr = (bf16x8){0, 0, 0, 0, 0, 0, 0, 0};
                if (valid) bfr = *(const bf16x8*)&wrow[ks * 32 + kb];
                acc = __builtin_amdgcn_mfma_f32_16x16x32_bf16(af, bfr, acc, 0, 0, 0);
            }
            int ncol = w * 16 + (l & 15);
            if (ncol < 40) {
                #pragma unroll
                for (int r = 0; r < 4; r++) {
                    int t = (l >> 4) * 4 + r;
                    xdbl_lds[t][ncol] = acc[r];
                    xdbl[((size_t)b * TOK + tloc0 + t) * 40 + ncol] = acc[r];
                }
            }
        }
    }
    __syncthreads();

    // ---- [E] scan phase-1 (h0=0); packs {u,dtv},{z} into udb2 ----
    float a1 = a1s[d];
    bool pw = pwf[d] != 0;
    float w8[8];
    #pragma unroll
    for (int j = 0; j < 8; j++) w8[j] = dtw[d * 8 + j];
    float bias = dtb_[d];
    float h[16];
    #pragma unroll
    for (int n = 0; n < 16; n++) h[n] = 0.f;
    float sdt = 0.f;
    uint2* udp = udb + ((size_t)b * TOK + tloc0) * 256 + d;

    if (pw) {
        for (int t = 0; t < CHL; t++) {
            float acc = bias;
            #pragma unroll
            for (int j = 0; j < 8; j++) acc += xdbl_lds[t][j] * w8[j];
            float dtv = softplus_f(acc);
            ushort uraw = u_lds[t][d];
            ushort zraw = z_lds[t][d];
            float uu = __bfloat162float(*(bf16*)&uraw);
            sdt += dtv;
            float du = dtv * uu;
            float dA[16];
            dA[0] = __expf(dtv * a1);
            #pragma unroll
            for (int n = 1; n < 16; n++) dA[n] = dA[(n - 1) >> 1] * dA[n >> 1];
            #pragma unroll
            for (int n = 0; n < 16; n++)
                h[n] = dA[n] * h[n] + du * xdbl_lds[t][8 + n];
            bf16 dv = __float2bfloat16(dtv);
            udp[(size_t)t * 256] = make_uint2(
                (unsigned int)uraw | ((unsigned int)(*(ushort*)&dv) << 16),
                (unsigned int)zraw);
        }
    } else {
        float Av[16];
        #pragma unroll
        for (int n = 0; n < 16; n++) Av[n] = -__expf(A_log[d * 16 + n]);
        for (int t = 0; t < CHL; t++) {
            float acc = bias;
            #pragma unroll
            for (int j = 0; j < 8; j++) acc += xdbl_lds[t][j] * w8[j];
            float dtv = softplus_f(acc);
            ushort uraw = u_lds[t][d];
            ushort zraw = z_lds[t][d];
            float uu = __bfloat162float(*(bf16*)&uraw);
            sdt += dtv;
            float du = dtv * uu;
            #pragma unroll
            for (int n = 0; n < 16; n++)
                h[n] = __expf(dtv * Av[n]) * h[n] + du * xdbl_lds[t][8 + n];
            bf16 dv = __float2bfloat16(dtv);
            udp[(size_t)t * 256] = make_uint2(
                (unsigned int)uraw | ((unsigned int)(*(ushort*)&dv) << 16),
                (unsigned int)zraw);
        }
    }
    bf16* qp = q + ((size_t)blk * 16) * 256 + d;
    #pragma unroll
    for (int n = 0; n < 16; n++) qp[(size_t)n * 256] = __float2bfloat16(h[n]);
    sdt_out[(size_t)blk * 256 + d] = sdt;
}

// scan2: cross-chunk combine on bf16 qbuf; f32 accumulation.
__global__ __launch_bounds__(256) void k_scan2(
    const float* __restrict__ A_log, const float* __restrict__ sdt_in,
    bf16* __restrict__ q)
{
    int idx = blockIdx.x * 256 + threadIdx.x;   // 65536
    int d = idx & 255, n = (idx >> 8) & 15, b = idx >> 12;
    float Av = -__expf(A_log[d * 16 + n]);
    float h = 0.f;
    for (int g = 0; g < NCH / 8; g++) {
        float qv[8], sv[8];
        #pragma unroll
        for (int j = 0; j < 8; j++) {
            size_t blk = (size_t)b * NCH + g * 8 + j;
            qv[j] = __bfloat162float(q[(blk * 16 + n) * 256 + d]);
            sv[j] = sdt_in[blk * 256 + d];
        }
        #pragma unroll
        for (int j = 0; j < 8; j++) {
            size_t blk = (size_t)b * NCH + g * 8 + j;
            float P = __expf(Av * sv[j]);
            q[(blk * 16 + n) * 256 + d] = __float2bfloat16(h);
            h = P * h + qv[j];
        }
    }
}

// ---------------------------------------------------------------------------
// K6: scan3 (u,dtv,z from packed udb2) + out_proj + residual + next-RMSNorm.
// LDS: y(8448) + xn(8448) = 16.9 KB.
// ---------------------------------------------------------------------------
__global__ __launch_bounds__(256) void k_scan3o(
    const uint2* __restrict__ udb, const float* __restrict__ xdbl,
    const float* __restrict__ a1s, const int* __restrict__ pwf,
    const float* __restrict__ A_log, const float* __restrict__ Dp,
    const bf16* __restrict__ q, const bf16* __restrict__ ow,
    const float* __restrict__ nwn,
    float* __restrict__ x, bf16* __restrict__ hbf)
{
    int blk = blockIdx.x;
    int b = blk >> 6, ch = blk & (NCH - 1);
    int d = threadIdx.x;
    __shared__ ushort y_lds[16][264];
    __shared__ float xn_lds[16][132];

    size_t tok0 = (size_t)b * TOK + ch * CHL;

    float a1 = a1s[d];
    bool pw = pwf[d] != 0;
    float Dv = Dp[d];
    float h[16];
    const bf16* qp = q + ((size_t)blk * 16) * 256 + d;
    #pragma unroll
    for (int n = 0; n < 16; n++) h[n] = __bfloat162float(qp[(size_t)n * 256]);

    const float* row = xdbl + tok0 * 40;
    const uint2* up = udb + tok0 * 256 + d;

    if (pw) {
        for (int t = 0; t < CHL; t++, row += 40, up += 256) {
            uint2 ud = *up;
            ushort ulo = (ushort)(ud.x & 0xffffu), dhi = (ushort)(ud.x >> 16);
            ushort zraw = (ushort)(ud.y & 0xffffu);
            float uu = __bfloat162float(*(bf16*)&ulo);
            float dtv = __bfloat162float(*(bf16*)&dhi);
            float du = dtv * uu;
            float dA[16];
            dA[0] = __expf(dtv * a1);
            #pragma unroll
            for (int n = 1; n < 16; n++) dA[n] = dA[(n - 1) >> 1] * dA[n >> 1];
            float ya = 0.f;
            #pragma unroll
            for (int n = 0; n < 16; n++) {
                h[n] = dA[n] * h[n] + du * row[8 + n];
                ya += h[n] * row[24 + n];
            }
            float zv = __bfloat162float(*(bf16*)&zraw);
            float sz = __fdividef(zv, 1.f + __expf(-zv));
            bf16 yb = __float2bfloat16((ya + uu * Dv) * sz);
            y_lds[t][d] = *(ushort*)&yb;
        }
    } else {
        float Av[16];
        #pragma unroll
        for (int n = 0; n < 16; n++) Av[n] = -__expf(A_log[d * 16 + n]);
        for (int t = 0; t < CHL; t++, row += 40, up += 256) {
            uint2 ud = *up;
            ushort ulo = (ushort)(ud.x & 0xffffu), dhi = (ushort)(ud.x >> 16);
            ushort zraw = (ushort)(ud.y & 0xffffu);
            float uu = __bfloat162float(*(bf16*)&ulo);
            float dtv = __bfloat162float(*(bf16*)&dhi);
            float du = dtv * uu;
            float ya = 0.f;
            #pragma unroll
            for (int n = 0; n < 16; n++) {
                h[n] = __expf(dtv * Av[n]) * h[n] + du * row[8 + n];
                ya += h[n] * row[24 + n];
            }
            float zv = __bfloat162float(*(bf16*)&zraw);
            float sz = __fdividef(zv, 1.f + __expf(-zv));
            bf16 yb = __float2bfloat16((ya + uu * Dv) * sz);
            y_lds[t][d] = *(ushort*)&yb;
        }
    }
    __syncthreads();

    // ---- out_proj + residual ----
    int w = d >> 6, l = d & 63;
    int lr = l & 15, kb = (l >> 4) * 8;
    const bf16* wr0 = ow + (size_t)(w * 32 + lr) * 256;
    const bf16* wr1 = ow + (size_t)(w * 32 + 16 + lr) * 256;
    f32x4 acc0 = (f32x4){0.f, 0.f, 0.f, 0.f};
    f32x4 acc1 = (f32x4){0.f, 0.f, 0.f, 0.f};
    #pragma unroll
    for (int ks = 0; ks < 8; ks++) {
        bf16x8 af = *(const bf16x8*)&y_lds[lr][ks * 32 + kb];
        bf16x8 b0 = *(const bf16x8*)&wr0[ks * 32 + kb];
        bf16x8 b1 = *(const bf16x8*)&wr1[ks * 32 + kb];
        acc0 = __builtin_amdgcn_mfma_f32_16x16x32_bf16(af, b0, acc0, 0, 0, 0);
        acc1 = __builtin_amdgcn_mfma_f32_16x16x32_bf16(af, b1, acc1, 0, 0, 0);
    }
    int trow = (l >> 4) * 4;
    float* xp = x + (tok0 + trow) * (size_t)DMODEL;
    #pragma unroll
    for (int r = 0; r < 4; r++) {
        float v0 = xp[(size_t)r * DMODEL + w * 32 + lr] + acc0[r];
        float v1 = xp[(size_t)r * DMODEL + w * 32 + 16 + lr] + acc1[r];
        xp[(size_t)r * DMODEL + w * 32 + lr] = v0;
        xp[(size_t)r * DMODEL + w * 32 + 16 + lr] = v1;
        xn_lds[trow + r][w * 32 + lr] = v0;
        xn_lds[trow + r][w * 32 + 16 + lr] = v1;
    }
    __syncthreads();

    // ---- fused RMSNorm for next consumer ----
    {
        int t = d >> 4, g = d & 15;
        float vals[8];
        float ss = 0.f;
        #pragma unroll
        for (int j = 0; j < 8; j++) { vals[j] = xn_lds[t][g * 8 + j]; ss += vals[j] * vals[j]; }
        ss += __shfl_xor(ss, 1, 64);
        ss += __shfl_xor(ss, 2, 64);
        ss += __shfl_xor(ss, 4, 64);
        ss += __shfl_xor(ss, 8, 64);
        float rms = rsqrtf(ss * (1.f / DMODEL) + EPSF);
        bf16* hp = hbf + (tok0 + t) * (size_t)DMODEL;
        #pragma unroll
        for (int j = 0; j < 8; j++)
            hp[g * 8 + j] = __float2bfloat16(vals[j] * rms * nwn[g * 8 + j]);
    }
}

// ---------------------------------------------------------------------------
// K7: head epilogue
// ---------------------------------------------------------------------------
__global__ __launch_bounds__(256) void k_head_ep(
    const float* __restrict__ hg, const float* __restrict__ hb,
    const float* __restrict__ means, const float* __restrict__ stdev,
    float* __restrict__ out)
{
    int i = blockIdx.x * 256 + threadIdx.x;
    if (i >= BATCH * PRED * NVARS) return;
    int c = i & 31;
    int p = (i >> 5) % PRED;
    int b = i / (PRED * NVARS);
    float v = hg[((size_t)b * NVARS + c) * PRED + p] + hb[p];
    out[i] = v * stdev[b * NVARS + c] + means[b * NVARS + c];
}

// ---------------------------------------------------------------------------
extern "C" void kernel_launch(void* const* d_in, const int* in_sizes, int n_in,
                              void* d_out, int out_size, void* d_ws, size_t ws_size,
                              hipStream_t stream)
{
    const float* x_enc   = (const float*)d_in[0];
    const float* patch_w = (const float*)d_in[4];
    const float* norm_w  = (const float*)d_in[5];
    const float* in_w    = (const float*)d_in[6];
    const float* conv_w  = (const float*)d_in[7];
    const float* conv_b  = (const float*)d_in[8];
    const float* xp_w    = (const float*)d_in[9];
    const float* dt_w    = (const float*)d_in[10];
    const float* dt_b    = (const float*)d_in[11];
    const float* A_log   = (const float*)d_in[12];
    const float* D_skip  = (const float*)d_in[13];
    const float* out_w   = (const float*)d_in[14];
    const float* fnorm_w = (const float*)d_in[15];
    const float* head_w  = (const float*)d_in[16];
    const float* head_b  = (const float*)d_in[17];
    float* out = (float*)d_out;

    float* ws    = (float*)d_ws;
    float* means = ws;                          // 512
    float* stdv  = ws + 512;                    // 512
    float* x     = ws + 1024;                   // NTOK*128 f32   8MB
    float* xdbl  = x    + (size_t)NTOK * 128;   // NTOK*40      2.6MB
    float* sbuf  = xdbl + (size_t)NTOK * 40;    // 16*64*256     1MB
    float* hg    = sbuf + (size_t)BATCH * NCH * DIN;   // 512*96
    float* a1s   = hg + 512 * PRED;             // NLAYER*DIN
    int*   pwf   = (int*)(a1s + NLAYER * DIN);  // NLAYER*DIN
    uint2* udb   = (uint2*)(pwf + NLAYER * DIN);       // NTOK*256 uint2 32MB
    bf16* hbf  = (bf16*)(udb + (size_t)NTOK * 256);    // NTOK*128   4MB
    bf16* qbuf = hbf + (size_t)NTOK * 128;      // 16*64*16*256 8.4MB
    bf16* wbf  = qbuf + (size_t)BATCH * NCH * DSTATE * DIN;  // 1.2MB

    bf16* iwbf = wbf;
    bf16* xwbf = iwbf + NIW;
    bf16* owbf = xwbf + NXW;
    bf16* hwbf = owbf + NOW;

    int castN = TOTW + NLAYER * DIN + 512 * PRED;
    int initBlocks = BATCH * NVARS + (castN + 255) / 256;
    k_init<<<initBlocks, 256, 0, stream>>>(
        x_enc, patch_w, norm_w, in_w, xp_w, out_w, head_w, A_log,
        x, hbf, means, stdv, wbf, a1s, pwf, hg);

    for (int layer = 0; layer < NLAYER; layer++) {
        const float* cw  = conv_w + layer * DIN * DCONV;
        const float* cb  = conv_b + layer * DIN;
        const float* dw  = dt_w   + layer * DIN * DTRANK;
        const float* db  = dt_b   + layer * DIN;
        const float* al  = A_log  + layer * DIN * DSTATE;
        const float* dp  = D_skip + layer * DIN;
        const float* a1l = a1s + layer * DIN;
        const int*   pwl = pwf + layer * DIN;
        const bf16* iwA = iwbf + (size_t)layer * 2 * DIN * DMODEL;
        const bf16* iwZ = iwA + (size_t)DIN * DMODEL;
        const bf16* xw = xwbf + (size_t)layer * (DTRANK + 2 * DSTATE) * DIN;
        const bf16* ow = owbf + (size_t)layer * DMODEL * DIN;
        const float* nwn = (layer + 1 < NLAYER) ? (norm_w + (layer + 1) * DMODEL) : fnorm_w;

        k_convx1<<<BATCH * NCH, 256, 0, stream>>>(
            hbf, iwA, iwZ, cw, cb, xw, dw, db, a1l, pwl, al, udb, xdbl, qbuf, sbuf);
        k_scan2<<<(BATCH * DIN * DSTATE) / 256, 256, 0, stream>>>(al, sbuf, qbuf);
        k_scan3o<<<BATCH * NCH, 256, 0, stream>>>(
            udb, xdbl, a1l, pwl, al, dp, qbuf, ow, nwn, x, hbf);
    }

    mfma_gemm_at<<<dim3(1, 4, 32), 256, 0, stream>>>(
        hbf, hwbf, hg, 512, PRED, LTOK * DMODEL, 128);
    k_head_ep<<<(BATCH * PRED * NVARS + 255) / 256, 256, 0, stream>>>(
        hg, head_b, means, stdv, out);
}

// Round 16
// 147.068 us; speedup vs baseline: 1.0885x; 1.0885x over previous
//
#include <hip/hip_runtime.h>
#include <hip/hip_bf16.h>
#include <math.h>

#define BATCH   16
#define SEQL    512
#define NVARS   32
#define PATCHL  16
#define LTOK    32
#define DMODEL  128
#define NLAYER  2
#define DIN     256
#define DSTATE  16
#define DTRANK  8
#define DCONV   4
#define PRED    96
#define TOK     1024
#define NTOK    (BATCH*TOK)   // 16384
#define EPSF    1e-5f
#define NCH     64            // time chunks
#define CHL     16            // TOK/NCH

#define NIW (NLAYER * 2 * DIN * DMODEL)          // 131072
#define NXW (NLAYER * (DTRANK + 2*DSTATE) * DIN) // 20480
#define NOW (NLAYER * DMODEL * DIN)              // 65536
#define NHW (PRED * LTOK * DMODEL)               // 393216
#define TOTW (NIW + NXW + NOW + NHW)

typedef __attribute__((ext_vector_type(8))) short bf16x8;
typedef __attribute__((ext_vector_type(4))) float f32x4;
typedef __hip_bfloat16 bf16;

__device__ __forceinline__ float softplus_f(float x) {
    return (x > 8.f) ? x : __logf(1.f + __expf(x));
}

// ---------------------------------------------------------------------------
// K0: merged init (instnorm+patch+rmsnorm0 | weight cast + consts + hg zero)
// ---------------------------------------------------------------------------
__global__ __launch_bounds__(256) void k_init(
    const float* __restrict__ x_enc, const float* __restrict__ patch_w,
    const float* __restrict__ nw0,
    const float* __restrict__ in_w, const float* __restrict__ xp_w,
    const float* __restrict__ out_w, const float* __restrict__ head_w,
    const float* __restrict__ A_log,
    float* __restrict__ x, bf16* __restrict__ hbf,
    float* __restrict__ means, float* __restrict__ stdev,
    bf16* __restrict__ wbf, float* __restrict__ a1s, int* __restrict__ pwf,
    float* __restrict__ hg)
{
    __shared__ float xe[SEQL];
    __shared__ float pw[DMODEL * PATCHL];
    __shared__ float red[8];
    __shared__ float enc_lds[LTOK][DMODEL];
    int tid = threadIdx.x;

    if (blockIdx.x >= BATCH * NVARS) {
        int i = (blockIdx.x - BATCH * NVARS) * 256 + tid;
        if (i < TOTW) {
            float v;
            if (i < NIW) v = in_w[i];
            else if (i < NIW + NXW) v = xp_w[i - NIW];
            else if (i < NIW + NXW + NOW) v = out_w[i - NIW - NXW];
            else v = head_w[i - NIW - NXW - NOW];
            wbf[i] = __float2bfloat16(v);
        } else if (i < TOTW + NLAYER * DIN) {
            int j = i - TOTW;
            const float* al = A_log + (size_t)j * DSTATE;
            float a1 = -__expf(al[0]);
            bool pwok = true;
            #pragma unroll
            for (int n = 1; n < 16; n++) {
                float av = -__expf(al[n]);
                pwok = pwok && (fabsf(av - (n + 1) * a1) <= 1e-5f * fabsf((n + 1) * a1));
            }
            a1s[j] = a1;
            pwf[j] = pwok ? 1 : 0;
        } else if (i < TOTW + NLAYER * DIN + 512 * PRED) {
            hg[i - TOTW - NLAYER * DIN] = 0.f;
        }
        return;
    }

    int bc = blockIdx.x;
    int b = bc >> 5, c = bc & 31;

    float v0 = x_enc[((size_t)b * SEQL + tid) * NVARS + c];
    float v1 = x_enc[((size_t)b * SEQL + tid + 256) * NVARS + c];
    for (int i = tid; i < DMODEL * PATCHL; i += 256) pw[i] = patch_w[i];

    float s = v0 + v1;
    for (int o = 1; o < 64; o <<= 1) s += __shfl_xor(s, o, 64);
    if ((tid & 63) == 0) red[tid >> 6] = s;
    __syncthreads();
    float mean = (red[0] + red[1] + red[2] + red[3]) * (1.f / 512.f);

    float d0 = v0 - mean, d1 = v1 - mean;
    float q = d0 * d0 + d1 * d1;
    for (int o = 1; o < 64; o <<= 1) q += __shfl_xor(q, o, 64);
    if ((tid & 63) == 0) red[4 + (tid >> 6)] = q;
    __syncthreads();
    float var = (red[4] + red[5] + red[6] + red[7]) * (1.f / 512.f);
    float sd = sqrtf(var + EPSF);
    float rsd = 1.f / sd;
    if (tid == 0) { means[bc] = mean; stdev[bc] = sd; }

    xe[tid] = d0 * rsd;
    xe[tid + 256] = d1 * rsd;
    __syncthreads();

    size_t base = ((size_t)b * TOK + (size_t)c * LTOK) * DMODEL;
    for (int o = tid; o < LTOK * DMODEL; o += 256) {
        int l = o >> 7, dm = o & 127;
        float acc = 0.f;
        #pragma unroll
        for (int p = 0; p < PATCHL; p++) acc += xe[l * PATCHL + p] * pw[dm * PATCHL + p];
        x[base + o] = acc;
        enc_lds[l][dm] = acc;
    }
    __syncthreads();

    int t = tid >> 3, g = tid & 7;
    float vals[16];
    float ss = 0.f;
    #pragma unroll
    for (int j = 0; j < 16; j++) { vals[j] = enc_lds[t][g * 16 + j]; ss += vals[j] * vals[j]; }
    ss += __shfl_xor(ss, 1, 64);
    ss += __shfl_xor(ss, 2, 64);
    ss += __shfl_xor(ss, 4, 64);
    float rms = rsqrtf(ss * (1.f / DMODEL) + EPSF);
    bf16* hp = hbf + (base + (size_t)t * DMODEL);
    #pragma unroll
    for (int j = 0; j < 16; j++)
        hp[g * 16 + j] = __float2bfloat16(vals[j] * rms * nw0[g * 16 + j]);
}

// ---------------------------------------------------------------------------
// head GEMM (split-K atomicAdd)
// ---------------------------------------------------------------------------
__global__ __launch_bounds__(256) void mfma_gemm_at(
    const bf16* __restrict__ A, const bf16* __restrict__ W,
    float* __restrict__ C, int M, int N, int K, int kper)
{
    __shared__ ushort Asm[128][40];
    __shared__ ushort Wsm[128][40];
    int bm = blockIdx.y * 128, bn = blockIdx.x * 128;
    int tid = threadIdx.x;
    int w = tid >> 6, l = tid & 63;
    int wr = w >> 1, wc = w & 1;
    int kb = (l >> 4) * 8, lr = l & 15;

    f32x4 acc[4][4];
    #pragma unroll
    for (int i = 0; i < 4; i++)
        #pragma unroll
        for (int j = 0; j < 4; j++) acc[i][j] = (f32x4){0.f, 0.f, 0.f, 0.f};

    int kbeg = blockIdx.z * kper;
    for (int k0 = kbeg; k0 < kbeg + kper; k0 += 32) {
        #pragma unroll
        for (int i = 0; i < 2; i++) {
            int idx = tid + 256 * i;
            int row = idx >> 2, kq = (idx & 3) * 8;
            *(float4*)&Asm[row][kq] =
                *(const float4*)&A[(size_t)(bm + row) * K + k0 + kq];
            float4 wv = make_float4(0.f, 0.f, 0.f, 0.f);
            if (bn + row < N)
                wv = *(const float4*)&W[(size_t)(bn + row) * K + k0 + kq];
            *(float4*)&Wsm[row][kq] = wv;
        }
        __syncthreads();
        bf16x8 af[4], bfr[4];
        #pragma unroll
        for (int f = 0; f < 4; f++) {
            af[f]  = *(const bf16x8*)&Asm[wr * 64 + f * 16 + lr][kb];
            bfr[f] = *(const bf16x8*)&Wsm[wc * 64 + f * 16 + lr][kb];
        }
        #pragma unroll
        for (int mf = 0; mf < 4; mf++)
            #pragma unroll
            for (int nf = 0; nf < 4; nf++)
                acc[mf][nf] = __builtin_amdgcn_mfma_f32_16x16x32_bf16(
                    af[mf], bfr[nf], acc[mf][nf], 0, 0, 0);
        __syncthreads();
    }

    int rbase = bm + wr * 64 + (l >> 4) * 4;
    int cbase = bn + wc * 64 + lr;
    #pragma unroll
    for (int mf = 0; mf < 4; mf++) {
        #pragma unroll
        for (int nf = 0; nf < 4; nf++) {
            int n = cbase + nf * 16;
            if (n >= N) continue;
            #pragma unroll
            for (int r = 0; r < 4; r++)
                atomicAdd(&C[(size_t)(rbase + mf * 16 + r) * N + n], acc[mf][nf][r]);
        }
    }
}

// ---------------------------------------------------------------------------
// K4: fused in_proj(xs) MFMA + conv+SiLU + x_proj MFMA + scan1.
// LDS union: u over hb (dead after xs-MFMA), xdbl over xs (dead after conv).
// ---------------------------------------------------------------------------
__global__ __launch_bounds__(256) void k_convx1(
    const bf16* __restrict__ hbf, const bf16* __restrict__ iwA,
    const float* __restrict__ cw, const float* __restrict__ cb,
    const bf16* __restrict__ xw,
    const float* __restrict__ dtw, const float* __restrict__ dtb_,
    const float* __restrict__ a1s, const int* __restrict__ pwf,
    const float* __restrict__ A_log,
    unsigned int* __restrict__ udb, float* __restrict__ xdbl,
    bf16* __restrict__ q, float* __restrict__ sdt_out)
{
    int blk = blockIdx.x;              // b*NCH + ch
    int b = blk >> 6, ch = blk & (NCH - 1);
    int d = threadIdx.x;
    __shared__ __align__(16) char smem[25600];
    ushort (*hb_lds)[136] = (ushort(*)[136])smem;           // A (8704 B)
    ushort (*xs_lds)[264] = (ushort(*)[264])(smem + 8704);  // A-B (16896 B)
    ushort (*u_lds)[264]  = (ushort(*)[264])smem;           // B+ over hb (8448 B)
    float  (*xdbl_lds)[40] = (float(*)[40])(smem + 8704);   // C+ over xs (2560 B)

    int tloc0 = ch * CHL;

    // ---- [A] stage hbf tile (zero for tl<0) ----
    {
        int r = d >> 3, c8 = (d & 7) * 16;
        int tl = tloc0 - 16 + r;
        float4 v0 = make_float4(0.f, 0.f, 0.f, 0.f), v1 = v0;
        if (tl >= 0) {
            const bf16* src = hbf + ((size_t)b * TOK + tl) * DMODEL + c8;
            v0 = *(const float4*)src;
            v1 = *(const float4*)(src + 8);
        }
        *(float4*)&hb_lds[r][c8] = v0;
        *(float4*)&hb_lds[r][c8 + 8] = v1;
    }
    __syncthreads();

    // ---- xs = hbf @ iwA^T  (M=32, N=256, K=128) ----
    {
        int w = d >> 6, l = d & 63;
        int lr = l & 15, kb = (l >> 4) * 8;
        f32x4 accx[2][4];
        #pragma unroll
        for (int mf = 0; mf < 2; mf++)
            #pragma unroll
            for (int nf = 0; nf < 4; nf++) accx[mf][nf] = (f32x4){0.f, 0.f, 0.f, 0.f};
        #pragma unroll
        for (int ks = 0; ks < 4; ks++) {
            bf16x8 af0 = *(const bf16x8*)&hb_lds[lr][ks * 32 + kb];
            bf16x8 af1 = *(const bf16x8*)&hb_lds[16 + lr][ks * 32 + kb];
            #pragma unroll
            for (int nf = 0; nf < 4; nf++) {
                const bf16* wrow = iwA + (size_t)(w * 64 + nf * 16 + lr) * DMODEL;
                bf16x8 bfr = *(const bf16x8*)&wrow[ks * 32 + kb];
                accx[0][nf] = __builtin_amdgcn_mfma_f32_16x16x32_bf16(af0, bfr, accx[0][nf], 0, 0, 0);
                accx[1][nf] = __builtin_amdgcn_mfma_f32_16x16x32_bf16(af1, bfr, accx[1][nf], 0, 0, 0);
            }
        }
        __syncthreads();   // hb reads complete before u overwrites it later
        #pragma unroll
        for (int mf = 0; mf < 2; mf++)
            #pragma unroll
            for (int nf = 0; nf < 4; nf++) {
                int ncol = w * 64 + nf * 16 + lr;
                #pragma unroll
                for (int r = 0; r < 4; r++) {
                    int row = mf * 16 + (l >> 4) * 4 + r;
                    bf16 xb = __float2bfloat16(accx[mf][nf][r]);
                    xs_lds[row][ncol] = *(ushort*)&xb;
                }
            }
    }
    __syncthreads();

    // ---- [B] conv + SiLU -> u_lds (over dead hb) ----
    {
        float c0 = cw[d * 4], c1 = cw[d * 4 + 1], c2 = cw[d * 4 + 2], c3 = cw[d * 4 + 3];
        float cbias = cb[d];
        float xv[19];
        #pragma unroll
        for (int i = 0; i < 19; i++) {
            ushort raw = xs_lds[13 + i][d];
            xv[i] = __bfloat162float(*(bf16*)&raw);
        }
        #pragma unroll
        for (int t = 0; t < 16; t++) {
            float a = cbias + xv[t] * c0 + xv[t + 1] * c1 + xv[t + 2] * c2 + xv[t + 3] * c3;
            float s = __fdividef(a, 1.f + __expf(-a));
            bf16 ub = __float2bfloat16(s);
            u_lds[t][d] = *(ushort*)&ub;
        }
    }
    __syncthreads();

    // ---- [C] x_proj: xdbl = u @ xw^T (xdbl over dead xs), 3 waves ----
    {
        int w = d >> 6, l = d & 63;
        if (w < 3) {
            int lr = l & 15, kb = (l >> 4) * 8;
            int nrow = w * 16 + lr;
            bool valid = nrow < 40;
            const bf16* wrow = xw + (size_t)nrow * 256;
            f32x4 acc = (f32x4){0.f, 0.f, 0.f, 0.f};
            #pragma unroll
            for (int ks = 0; ks < 8; ks++) {
                bf16x8 af = *(const bf16x8*)&u_lds[lr][ks * 32 + kb];
                bf16x8 bfr = (bf16x8){0, 0, 0, 0, 0, 0, 0, 0};
                if (valid) bfr = *(const bf16x8*)&wrow[ks * 32 + kb];
                acc = __builtin_amdgcn_mfma_f32_16x16x32_bf16(af, bfr, acc, 0, 0, 0);
            }
            int ncol = w * 16 + (l & 15);
            if (ncol < 40) {
                #pragma unroll
                for (int r = 0; r < 4; r++) {
                    int t = (l >> 4) * 4 + r;
                    xdbl_lds[t][ncol] = acc[r];
                    xdbl[((size_t)b * TOK + tloc0 + t) * 40 + ncol] = acc[r];
                }
            }
        }
    }
    __syncthreads();

    // ---- [D] scan phase-1 (h0 = 0); stores packed {u, dtv} ----
    float a1 = a1s[d];
    bool pw = pwf[d] != 0;
    float w8[8];
    #pragma unroll
    for (int j = 0; j < 8; j++) w8[j] = dtw[d * 8 + j];
    float bias = dtb_[d];
    float h[16];
    #pragma unroll
    for (int n = 0; n < 16; n++) h[n] = 0.f;
    float sdt = 0.f;
    unsigned int* udp = udb + ((size_t)b * TOK + tloc0) * 256 + d;

    if (pw) {
        for (int t = 0; t < CHL; t++) {
            float acc = bias;
            #pragma unroll
            for (int j = 0; j < 8; j++) acc += xdbl_lds[t][j] * w8[j];
            float dtv = softplus_f(acc);
            ushort uraw = u_lds[t][d];
            float uu = __bfloat162float(*(bf16*)&uraw);
            sdt += dtv;
            float du = dtv * uu;
            float dA[16];
            dA[0] = __expf(dtv * a1);
            #pragma unroll
            for (int n = 1; n < 16; n++) dA[n] = dA[(n - 1) >> 1] * dA[n >> 1];
            #pragma unroll
            for (int n = 0; n < 16; n++)
                h[n] = dA[n] * h[n] + du * xdbl_lds[t][8 + n];
            bf16 dv = __float2bfloat16(dtv);
            udp[(size_t)t * 256] = (unsigned int)uraw | ((unsigned int)(*(ushort*)&dv) << 16);
        }
    } else {
        float Av[16];
        #pragma unroll
        for (int n = 0; n < 16; n++) Av[n] = -__expf(A_log[d * 16 + n]);
        for (int t = 0; t < CHL; t++) {
            float acc = bias;
            #pragma unroll
            for (int j = 0; j < 8; j++) acc += xdbl_lds[t][j] * w8[j];
            float dtv = softplus_f(acc);
            ushort uraw = u_lds[t][d];
            float uu = __bfloat162float(*(bf16*)&uraw);
            sdt += dtv;
            float du = dtv * uu;
            #pragma unroll
            for (int n = 0; n < 16; n++)
                h[n] = __expf(dtv * Av[n]) * h[n] + du * xdbl_lds[t][8 + n];
            bf16 dv = __float2bfloat16(dtv);
            udp[(size_t)t * 256] = (unsigned int)uraw | ((unsigned int)(*(ushort*)&dv) << 16);
        }
    }
    bf16* qp = q + ((size_t)blk * 16) * 256 + d;
    #pragma unroll
    for (int n = 0; n < 16; n++) qp[(size_t)n * 256] = __float2bfloat16(h[n]);
    sdt_out[(size_t)blk * 256 + d] = sdt;
}

// scan2: cross-chunk combine on bf16 qbuf; f32 accumulation.
__global__ __launch_bounds__(256) void k_scan2(
    const float* __restrict__ A_log, const float* __restrict__ sdt_in,
    bf16* __restrict__ q)
{
    int idx = blockIdx.x * 256 + threadIdx.x;   // 65536
    int d = idx & 255, n = (idx >> 8) & 15, b = idx >> 12;
    float Av = -__expf(A_log[d * 16 + n]);
    float h = 0.f;
    for (int g = 0; g < NCH / 8; g++) {
        float qv[8], sv[8];
        #pragma unroll
        for (int j = 0; j < 8; j++) {
            size_t blk = (size_t)b * NCH + g * 8 + j;
            qv[j] = __bfloat162float(q[(blk * 16 + n) * 256 + d]);
            sv[j] = sdt_in[blk * 256 + d];
        }
        #pragma unroll
        for (int j = 0; j < 8; j++) {
            size_t blk = (size_t)b * NCH + g * 8 + j;
            float P = __expf(Av * sv[j]);
            q[(blk * 16 + n) * 256 + d] = __float2bfloat16(h);
            h = P * h + qv[j];
        }
    }
}

// ---------------------------------------------------------------------------
// K6: fused in_proj(z) MFMA + scan3 + out_proj + residual + next-RMSNorm.
// LDS union: xn over hz+z (dead after scan loop).
// ---------------------------------------------------------------------------
__global__ __launch_bounds__(256) void k_scan3o(
    const unsigned int* __restrict__ udb, const float* __restrict__ xdbl,
    const bf16* __restrict__ iwZ,
    const float* __restrict__ a1s, const int* __restrict__ pwf,
    const float* __restrict__ A_log, const float* __restrict__ Dp,
    const bf16* __restrict__ q, const bf16* __restrict__ ow,
    const float* __restrict__ nwn,
    float* __restrict__ x, bf16* __restrict__ hbf)
{
    int blk = blockIdx.x;
    int b = blk >> 6, ch = blk & (NCH - 1);
    int d = threadIdx.x;
    __shared__ __align__(16) char smem[21248];
    ushort (*hz_lds)[136] = (ushort(*)[136])smem;            // 4352 B
    ushort (*z_lds)[264]  = (ushort(*)[264])(smem + 4352);   // 8448 B
    ushort (*y_lds)[264]  = (ushort(*)[264])(smem + 12800);  // 8448 B
    float  (*xn_lds)[132] = (float(*)[132])smem;             // 8448 over hz+z

    size_t tok0 = (size_t)b * TOK + ch * CHL;

    // ---- stage own hbf rows ----
    {
        int r = d >> 4, c8 = (d & 15) * 8;
        *(float4*)&hz_lds[r][c8] = *(const float4*)(hbf + (tok0 + r) * DMODEL + c8);
    }
    __syncthreads();

    // ---- z = hbf @ iwZ^T  (M=16, N=256, K=128), 4 waves ----
    {
        int w = d >> 6, l = d & 63;
        int lr = l & 15, kb = (l >> 4) * 8;
        f32x4 accz[4];
        #pragma unroll
        for (int nf = 0; nf < 4; nf++) accz[nf] = (f32x4){0.f, 0.f, 0.f, 0.f};
        #pragma unroll
        for (int ks = 0; ks < 4; ks++) {
            bf16x8 af = *(const bf16x8*)&hz_lds[lr][ks * 32 + kb];
            #pragma unroll
            for (int nf = 0; nf < 4; nf++) {
                const bf16* wrow = iwZ + (size_t)(w * 64 + nf * 16 + lr) * DMODEL;
                bf16x8 bfr = *(const bf16x8*)&wrow[ks * 32 + kb];
                accz[nf] = __builtin_amdgcn_mfma_f32_16x16x32_bf16(af, bfr, accz[nf], 0, 0, 0);
            }
        }
        #pragma unroll
        for (int nf = 0; nf < 4; nf++) {
            int ncol = w * 64 + nf * 16 + lr;
            #pragma unroll
            for (int r = 0; r < 4; r++) {
                bf16 zb = __float2bfloat16(accz[nf][r]);
                z_lds[(l >> 4) * 4 + r][ncol] = *(ushort*)&zb;
            }
        }
    }
    __syncthreads();

    // ---- scan phase-3: dtv+u from packed buffer ----
    float a1 = a1s[d];
    bool pw = pwf[d] != 0;
    float Dv = Dp[d];
    float h[16];
    const bf16* qp = q + ((size_t)blk * 16) * 256 + d;
    #pragma unroll
    for (int n = 0; n < 16; n++) h[n] = __bfloat162float(qp[(size_t)n * 256]);

    const float* row = xdbl + tok0 * 40;
    const unsigned int* up = udb + tok0 * 256 + d;

    if (pw) {
        for (int t = 0; t < CHL; t++, row += 40, up += 256) {
            unsigned int ud = *up;
            ushort ulo = (ushort)(ud & 0xffffu), dhi = (ushort)(ud >> 16);
            float uu = __bfloat162float(*(bf16*)&ulo);
            float dtv = __bfloat162float(*(bf16*)&dhi);
            float du = dtv * uu;
            float dA[16];
            dA[0] = __expf(dtv * a1);
            #pragma unroll
            for (int n = 1; n < 16; n++) dA[n] = dA[(n - 1) >> 1] * dA[n >> 1];
            float ya = 0.f;
            #pragma unroll
            for (int n = 0; n < 16; n++) {
                h[n] = dA[n] * h[n] + du * row[8 + n];
                ya += h[n] * row[24 + n];
            }
            ushort zraw = z_lds[t][d];
            float zv = __bfloat162float(*(bf16*)&zraw);
            float sz = __fdividef(zv, 1.f + __expf(-zv));
            bf16 yb = __float2bfloat16((ya + uu * Dv) * sz);
            y_lds[t][d] = *(ushort*)&yb;
        }
    } else {
        float Av[16];
        #pragma unroll
        for (int n = 0; n < 16; n++) Av[n] = -__expf(A_log[d * 16 + n]);
        for (int t = 0; t < CHL; t++, row += 40, up += 256) {
            unsigned int ud = *up;
            ushort ulo = (ushort)(ud & 0xffffu), dhi = (ushort)(ud >> 16);
            float uu = __bfloat162float(*(bf16*)&ulo);
            float dtv = __bfloat162float(*(bf16*)&dhi);
            float du = dtv * uu;
            float ya = 0.f;
            #pragma unroll
            for (int n = 0; n < 16; n++) {
                h[n] = __expf(dtv * Av[n]) * h[n] + du * row[8 + n];
                ya += h[n] * row[24 + n];
            }
            ushort zraw = z_lds[t][d];
            float zv = __bfloat162float(*(bf16*)&zraw);
            float sz = __fdividef(zv, 1.f + __expf(-zv));
            bf16 yb = __float2bfloat16((ya + uu * Dv) * sz);
            y_lds[t][d] = *(ushort*)&yb;
        }
    }
    __syncthreads();

    // ---- out_proj + residual; xn over dead hz/z ----
    int w = d >> 6, l = d & 63;
    int lr = l & 15, kb = (l >> 4) * 8;
    const bf16* wr0 = ow + (size_t)(w * 32 + lr) * 256;
    const bf16* wr1 = ow + (size_t)(w * 32 + 16 + lr) * 256;
    f32x4 acc0 = (f32x4){0.f, 0.f, 0.f, 0.f};
    f32x4 acc1 = (f32x4){0.f, 0.f, 0.f, 0.f};
    #pragma unroll
    for (int ks = 0; ks < 8; ks++) {
        bf16x8 af = *(const bf16x8*)&y_lds[lr][ks * 32 + kb];
        bf16x8 b0 = *(const bf16x8*)&wr0[ks * 32 + kb];
        bf16x8 b1 = *(const bf16x8*)&wr1[ks * 32 + kb];
        acc0 = __builtin_amdgcn_mfma_f32_16x16x32_bf16(af, b0, acc0, 0, 0, 0);
        acc1 = __builtin_amdgcn_mfma_f32_16x16x32_bf16(af, b1, acc1, 0, 0, 0);
    }
    int trow = (l >> 4) * 4;
    float* xp = x + (tok0 + trow) * (size_t)DMODEL;
    #pragma unroll
    for (int r = 0; r < 4; r++) {
        float v0 = xp[(size_t)r * DMODEL + w * 32 + lr] + acc0[r];
        float v1 = xp[(size_t)r * DMODEL + w * 32 + 16 + lr] + acc1[r];
        xp[(size_t)r * DMODEL + w * 32 + lr] = v0;
        xp[(size_t)r * DMODEL + w * 32 + 16 + lr] = v1;
        xn_lds[trow + r][w * 32 + lr] = v0;
        xn_lds[trow + r][w * 32 + 16 + lr] = v1;
    }
    __syncthreads();

    // ---- fused RMSNorm for next consumer ----
    {
        int t = d >> 4, g = d & 15;
        float vals[8];
        float ss = 0.f;
        #pragma unroll
        for (int j = 0; j < 8; j++) { vals[j] = xn_lds[t][g * 8 + j]; ss += vals[j] * vals[j]; }
        ss += __shfl_xor(ss, 1, 64);
        ss += __shfl_xor(ss, 2, 64);
        ss += __shfl_xor(ss, 4, 64);
        ss += __shfl_xor(ss, 8, 64);
        float rms = rsqrtf(ss * (1.f / DMODEL) + EPSF);
        bf16* hp = hbf + (tok0 + t) * (size_t)DMODEL;
        #pragma unroll
        for (int j = 0; j < 8; j++)
            hp[g * 8 + j] = __float2bfloat16(vals[j] * rms * nwn[g * 8 + j]);
    }
}

// ---------------------------------------------------------------------------
// K7: head epilogue
// ---------------------------------------------------------------------------
__global__ __launch_bounds__(256) void k_head_ep(
    const float* __restrict__ hg, const float* __restrict__ hb,
    const float* __restrict__ means, const float* __restrict__ stdev,
    float* __restrict__ out)
{
    int i = blockIdx.x * 256 + threadIdx.x;
    if (i >= BATCH * PRED * NVARS) return;
    int c = i & 31;
    int p = (i >> 5) % PRED;
    int b = i / (PRED * NVARS);
    float v = hg[((size_t)b * NVARS + c) * PRED + p] + hb[p];
    out[i] = v * stdev[b * NVARS + c] + means[b * NVARS + c];
}

// ---------------------------------------------------------------------------
extern "C" void kernel_launch(void* const* d_in, const int* in_sizes, int n_in,
                              void* d_out, int out_size, void* d_ws, size_t ws_size,
                              hipStream_t stream)
{
    const float* x_enc   = (const float*)d_in[0];
    const float* patch_w = (const float*)d_in[4];
    const float* norm_w  = (const float*)d_in[5];
    const float* in_w    = (const float*)d_in[6];
    const float* conv_w  = (const float*)d_in[7];
    const float* conv_b  = (const float*)d_in[8];
    const float* xp_w    = (const float*)d_in[9];
    const float* dt_w    = (const float*)d_in[10];
    const float* dt_b    = (const float*)d_in[11];
    const float* A_log   = (const float*)d_in[12];
    const float* D_skip  = (const float*)d_in[13];
    const float* out_w   = (const float*)d_in[14];
    const float* fnorm_w = (const float*)d_in[15];
    const float* head_w  = (const float*)d_in[16];
    const float* head_b  = (const float*)d_in[17];
    float* out = (float*)d_out;

    float* ws    = (float*)d_ws;
    float* means = ws;                          // 512
    float* stdv  = ws + 512;                    // 512
    float* x     = ws + 1024;                   // NTOK*128 f32   8MB
    float* xdbl  = x    + (size_t)NTOK * 128;   // NTOK*40      2.6MB
    float* sbuf  = xdbl + (size_t)NTOK * 40;    // 16*64*256     1MB
    float* hg    = sbuf + (size_t)BATCH * NCH * DIN;   // 512*96
    float* a1s   = hg + 512 * PRED;             // NLAYER*DIN
    int*   pwf   = (int*)(a1s + NLAYER * DIN);  // NLAYER*DIN
    unsigned int* udb = (unsigned int*)(pwf + NLAYER * DIN);  // NTOK*256 u32 16MB
    bf16* hbf  = (bf16*)(udb + (size_t)NTOK * 256);    // NTOK*128   4MB
    bf16* qbuf = hbf + (size_t)NTOK * 128;      // 16*64*16*256 8.4MB
    bf16* wbf  = qbuf + (size_t)BATCH * NCH * DSTATE * DIN;  // 1.2MB

    bf16* iwbf = wbf;
    bf16* xwbf = iwbf + NIW;
    bf16* owbf = xwbf + NXW;
    bf16* hwbf = owbf + NOW;

    int castN = TOTW + NLAYER * DIN + 512 * PRED;
    int initBlocks = BATCH * NVARS + (castN + 255) / 256;
    k_init<<<initBlocks, 256, 0, stream>>>(
        x_enc, patch_w, norm_w, in_w, xp_w, out_w, head_w, A_log,
        x, hbf, means, stdv, wbf, a1s, pwf, hg);

    for (int layer = 0; layer < NLAYER; layer++) {
        const float* cw  = conv_w + layer * DIN * DCONV;
        const float* cb  = conv_b + layer * DIN;
        const float* dw  = dt_w   + layer * DIN * DTRANK;
        const float* db  = dt_b   + layer * DIN;
        const float* al  = A_log  + layer * DIN * DSTATE;
        const float* dp  = D_skip + layer * DIN;
        const float* a1l = a1s + layer * DIN;
        const int*   pwl = pwf + layer * DIN;
        const bf16* iwA = iwbf + (size_t)layer * 2 * DIN * DMODEL;
        const bf16* iwZ = iwA + (size_t)DIN * DMODEL;
        const bf16* xw = xwbf + (size_t)layer * (DTRANK + 2 * DSTATE) * DIN;
        const bf16* ow = owbf + (size_t)layer * DMODEL * DIN;
        const float* nwn = (layer + 1 < NLAYER) ? (norm_w + (layer + 1) * DMODEL) : fnorm_w;

        k_convx1<<<BATCH * NCH, 256, 0, stream>>>(
            hbf, iwA, cw, cb, xw, dw, db, a1l, pwl, al, udb, xdbl, qbuf, sbuf);
        k_scan2<<<(BATCH * DIN * DSTATE) / 256, 256, 0, stream>>>(al, sbuf, qbuf);
        k_scan3o<<<BATCH * NCH, 256, 0, stream>>>(
            udb, xdbl, iwZ, a1l, pwl, al, dp, qbuf, ow, nwn, x, hbf);
    }

    mfma_gemm_at<<<dim3(1, 4, 32), 256, 0, stream>>>(
        hbf, hwbf, hg, 512, PRED, LTOK * DMODEL, 128);
    k_head_ep<<<(BATCH * PRED * NVARS + 255) / 256, 256, 0, stream>>>(
        hg, head_b, means, stdv, out);
}